// Round 4
// baseline (1792.511 us; speedup 1.0000x reference)
//
#include <hip/hip_runtime.h>
#include <cstdint>
#include <cstddef>

typedef _Float16 f16;
typedef __attribute__((ext_vector_type(8))) _Float16 f16x8;
typedef __attribute__((ext_vector_type(4))) _Float16 f16x4;
typedef __attribute__((ext_vector_type(4))) float f32x4;

#define AS1 const __attribute__((address_space(1))) void*
#define AS3 __attribute__((address_space(3))) void*

__device__ __forceinline__ void gld_lds16(const void* g, void* l) {
    __builtin_amdgcn_global_load_lds((AS1)g, (AS3)l, 16, 0, 0);
}

// ---------------- prep: cast h to fp16 ----------------
__global__ __launch_bounds__(256) void cast_h(const float* __restrict__ in,
                                              f16* __restrict__ hh, int n4) {
    int i = blockIdx.x * 256 + threadIdx.x;
    if (i >= n4) return;
    f32x4 x = ((const f32x4*)in)[i];
    f16x4 a;
    #pragma unroll
    for (int j = 0; j < 4; ++j) a[j] = (f16)x[j];
    ((f16x4*)hh)[i] = a;
}

// ---------------- prep: weights (transposed, qkv hi/lo split) ----------------
__global__ __launch_bounds__(256) void prep_weights(
    const float* __restrict__ Wv, const float* __restrict__ Wk, const float* __restrict__ Wq,
    const float* __restrict__ W1, const float* __restrict__ W2,
    const float* __restrict__ bq, const float* __restrict__ bk, const float* __restrict__ bv,
    f16* __restrict__ Wqkv_h, f16* __restrict__ Wqkv_l,
    f16* __restrict__ W1t, f16* __restrict__ W2t, float* __restrict__ bias_qkv) {
    int i = blockIdx.x * 256 + threadIdx.x;
    if (i < 1536 * 512) {
        int j = i >> 9, m = i & 511;   // j = output col (q|k|v), m = k index
        float w = (j < 512) ? Wq[m * 512 + j]
               : (j < 1024) ? Wk[m * 512 + (j - 512)]
                            : Wv[m * 512 + (j - 1024)];
        f16 hi = (f16)w;
        Wqkv_h[i] = hi;
        Wqkv_l[i] = (f16)(w - (float)hi);
    }
    if (i < 512 * 512) {
        int j = i >> 9, m = i & 511;
        W1t[i] = (f16)W1[m * 512 + j];
        W2t[i] = (f16)W2[m * 512 + j];
    }
    if (i < 1536) {
        bias_qkv[i] = (i < 512) ? bq[i] : (i < 1024) ? bk[i - 512] : bv[i - 1024];
    }
}

// ---------------- GEMM (NT: C[i,j] = sum_k A[i,k]*B[j,k]) ----------------
// TM x TN tile, BK=32, 4 waves (2x2), 16x16x32 f16 MFMA, double-buffered
// global_load_lds staging. NSEG>1 = concat-K split precision: the K-loop
// runs NSEG*16 steps, each 16-step segment pulling from a different (A,B)
// pointer pair — hi/lo cross terms without extra LDS or live fragments.
enum { MODE_QKV = 0, MODE_S = 1, MODE_PV = 2, MODE_HID = 3, MODE_FIN = 4 };

template <int MODE, int TM, int TN, int NSEG>
__global__ __launch_bounds__(256, 4) void gemm_nt(
    const f16* __restrict__ A0, const f16* __restrict__ A1, const f16* __restrict__ A2,
    int lda, long long sA,
    const f16* __restrict__ B0, const f16* __restrict__ B1, const f16* __restrict__ B2,
    int ldb, long long sB,
    void* __restrict__ C, int ldc, long long sC,
    const float* __restrict__ bias, int nK,
    f16* __restrict__ Qh, f16* __restrict__ Ql,
    f16* __restrict__ Kh, f16* __restrict__ Kl, f16* __restrict__ Vt)
{
    constexpr int ABYTES = TM * 32 * 2;
    constexpr int BBYTES = TN * 32 * 2;
    constexpr int MF = TM / 32;          // m-frags per wave
    constexpr int NW = TN / 32;          // n-frags per wave
    constexpr int AISS = TM / 64;        // A stage issues per wave
    constexpr int BISS = TN / 64;        // B stage issues per wave
    __shared__ alignas(16) char lds[2][ABYTES + BBYTES];

    const int lane = threadIdx.x & 63;
    const int wave = threadIdx.x >> 6;
    const int z = blockIdx.z;

    const f16* a0 = A0 + (long long)z * sA;
    const f16* a1 = A1 + (long long)z * sA;
    const f16* a2 = A2 + (long long)z * sA;
    const f16* b0 = B0 + (long long)z * sB;
    const f16* b1 = B1 + (long long)z * sB;
    const f16* b2 = B2 + (long long)z * sB;
    char* Cb = (char*)C + (long long)z * sC;

    const int rowBase = blockIdx.y * TM;
    const int colBase = blockIdx.x * TN;

    const int segr = lane >> 2;          // 16 rows per 1KB issue
    const int segk = (lane & 3) * 8;     // f16 elements

    auto stage = [&](int buf, int kt) {
        int seg, k0;
        if constexpr (NSEG > 1) { seg = kt >> 4; k0 = (kt & 15) << 5; }
        else                    { seg = 0;       k0 = kt << 5; }
        const f16* Ap = (seg == 0) ? a0 : (seg == 1 ? a1 : a2);
        const f16* Bp = (seg == 0) ? b0 : (seg == 1 ? b1 : b2);
        char* base = lds[buf];
        #pragma unroll
        for (int c = 0; c < AISS; ++c) {
            const int sg = wave * AISS + c;
            const int r = sg * 16 + segr;
            gld_lds16(Ap + (size_t)(rowBase + r) * lda + k0 + segk, base + sg * 1024);
        }
        #pragma unroll
        for (int c = 0; c < BISS; ++c) {
            const int sg = wave * BISS + c;
            const int r = sg * 16 + segr;
            gld_lds16(Bp + (size_t)(colBase + r) * ldb + k0 + segk,
                      base + ABYTES + sg * 1024);
        }
    };

    f32x4 acc[MF][NW] = {};
    stage(0, 0);

    const int wr = wave >> 1, wc = wave & 1;
    const int cl = lane & 15;
    const int kq = lane >> 4;
    const int kofs = kq * 8;

    for (int kt = 0; kt < nK; ++kt) {
        const int buf = kt & 1;
        __syncthreads();                 // drains vmcnt: current buffer ready
        if (kt + 1 < nK) stage(buf ^ 1, kt + 1);

        f16x8 ah[MF], bh[NW];
        const char* bufp = lds[buf];
        #pragma unroll
        for (int m = 0; m < MF; ++m)
            ah[m] = *(const f16x8*)(bufp + ((wr * (TM / 2) + m * 16 + cl) * 32 + kofs) * 2);
        #pragma unroll
        for (int n = 0; n < NW; ++n)
            bh[n] = *(const f16x8*)(bufp + ABYTES + ((wc * (TN / 2) + n * 16 + cl) * 32 + kofs) * 2);
        #pragma unroll
        for (int m = 0; m < MF; ++m)
            #pragma unroll
            for (int n = 0; n < NW; ++n)
                acc[m][n] = __builtin_amdgcn_mfma_f32_16x16x32_f16(ah[m], bh[n], acc[m][n], 0, 0, 0);
    }

    // ---- epilogue: C/D layout col = lane&15, row = (lane>>4)*4 + j ----
    #pragma unroll
    for (int m = 0; m < MF; ++m) {
        #pragma unroll
        for (int n = 0; n < NW; ++n) {
            const f32x4 a = acc[m][n];
            const int col = colBase + wc * (TN / 2) + n * 16 + cl;
            float bval = 0.f;
            if constexpr (MODE == MODE_QKV || MODE == MODE_HID || MODE == MODE_FIN)
                bval = bias[col];
            #pragma unroll
            for (int j = 0; j < 4; ++j) {
                const int row = rowBase + wr * (TM / 2) + m * 16 + kq * 4 + j;
                const float v = a[j] + bval;
                if constexpr (MODE == MODE_S) {
                    ((float*)Cb)[(size_t)row * ldc + col] = v;
                } else if constexpr (MODE == MODE_PV) {
                    ((f16*)Cb)[(size_t)row * ldc + col] = (f16)v;
                } else if constexpr (MODE == MODE_HID) {
                    ((f16*)Cb)[(size_t)row * ldc + col] = (f16)fmaxf(v, 0.f);
                } else if constexpr (MODE == MODE_FIN) {
                    ((float*)Cb)[(size_t)row * ldc + col] = v;
                } else {  // MODE_QKV: cols [0,512)=q, [512,1024)=k, [1024,1536)=v^T
                    if (col < 1024) {
                        const f16 hi = (f16)v;
                        const f16 lo = (f16)(v - (float)hi);
                        const size_t idx = (size_t)row * 512 + (col & 511);
                        if (col < 512) { Qh[idx] = hi; Ql[idx] = lo; }
                        else           { Kh[idx] = hi; Kl[idx] = lo; }
                    } else {
                        Vt[((size_t)(row >> 11) * 512 + (col - 1024)) * 2048 + (row & 2047)] = (f16)v;
                    }
                }
            }
        }
    }
}

// ---------------- softmax over rows of S (2048 cols), P fp16 in place ----------------
__global__ __launch_bounds__(256) void softmax_rows(float* __restrict__ S) {
    const int wave = threadIdx.x >> 6, lane = threadIdx.x & 63;
    float* rp = S + ((size_t)blockIdx.x * 4 + wave) * 2048;
    f32x4 v[8];
    float mx = -3.0e38f;
    #pragma unroll
    for (int s = 0; s < 8; ++s) {
        v[s] = ((const f32x4*)rp)[s * 64 + lane];
        mx = fmaxf(mx, fmaxf(fmaxf(v[s][0], v[s][1]), fmaxf(v[s][2], v[s][3])));
    }
    #pragma unroll
    for (int off = 32; off; off >>= 1) mx = fmaxf(mx, __shfl_xor(mx, off));
    float sum = 0.f;
    #pragma unroll
    for (int s = 0; s < 8; ++s)
        #pragma unroll
        for (int j = 0; j < 4; ++j) { const float e = __expf(v[s][j] - mx); v[s][j] = e; sum += e; }
    #pragma unroll
    for (int off = 32; off; off >>= 1) sum += __shfl_xor(sum, off);
    const float inv = 1.0f / sum;
    f16* op = (f16*)rp;   // overwrite first half of the row with fp16 P
    #pragma unroll
    for (int s = 0; s < 8; ++s) {
        f16x4 o;
        #pragma unroll
        for (int j = 0; j < 4; ++j) o[j] = (f16)(v[s][j] * inv);
        ((f16x4*)op)[s * 64 + lane] = o;
    }
}

extern "C" void kernel_launch(void* const* d_in, const int* in_sizes, int n_in,
                              void* d_out, int out_size, void* d_ws, size_t ws_size,
                              hipStream_t stream) {
    const float* h  = (const float*)d_in[1];
    const float* Wv = (const float*)d_in[2];
    const float* bv = (const float*)d_in[3];
    const float* Wk = (const float*)d_in[4];
    const float* bk = (const float*)d_in[5];
    const float* Wq = (const float*)d_in[6];
    const float* bq = (const float*)d_in[7];
    const float* W1 = (const float*)d_in[8];
    const float* b1 = (const float*)d_in[9];
    const float* W2 = (const float*)d_in[10];
    const float* b2 = (const float*)d_in[11];

    // ---- workspace (~196 MB, same layout that passed in round 3) ----
    char* p = (char*)d_ws;
    auto take = [&](size_t bytes) { char* r = p; p += (bytes + 255) & ~(size_t)255; return r; };

    const size_t QB = (size_t)32768 * 512 * 2;   // 32 MiB per qkv buffer
    f16* qh = (f16*)take(QB);
    f16* ql = (f16*)take(QB);
    f16* kh = (f16*)take(QB);
    f16* kl = (f16*)take(QB);
    f16* vt = (f16*)take(QB);                    // [b][h][n]
    float* S = (float*)take((size_t)2 * 2048 * 2048 * 4);   // 2-batch score chunk
    f16* Wqkvh = (f16*)take(1536 * 512 * 2);
    f16* Wqkvl = (f16*)take(1536 * 512 * 2);
    f16* W1t   = (f16*)take(512 * 512 * 2);
    f16* W2t   = (f16*)take(512 * 512 * 2);
    float* biasqkv = (float*)take(1536 * 4);
    // aliases (lifetime-disjoint, stream-ordered):
    f16* hh   = (f16*)S;  // fp16 h lives in S region until QKV completes (32 MiB exact)
    f16* outb = kl;       // PV[b] writes after S-GEMM[b]'s last read of kl[b]
    f16* hid  = qh;       // MLP1 writes after last S-GEMM read of qh

    cast_h<<<16384, 256, 0, stream>>>(h, hh, 4194304);
    prep_weights<<<3072, 256, 0, stream>>>(Wv, Wk, Wq, W1, W2, bq, bk, bv,
                                           Wqkvh, Wqkvl, W1t, W2t, biasqkv);
    // q,k,v = hh @ (Wh + Wl) + b : concat-K 2-segment split, LDS 32 KB
    gemm_nt<MODE_QKV, 128, 128, 2><<<dim3(12, 256, 1), 256, 0, stream>>>(
        hh, hh, nullptr, 512, 0,
        Wqkvh, Wqkvl, nullptr, 512, 0,
        nullptr, 0, 0, biasqkv, 32, qh, ql, kh, kl, vt);

    // attention, 2 batches per chunk (S region reused 8x)
    for (int c = 0; c < 8; ++c) {
        const long long off = (long long)c * 2 * 2048 * 512;  // f16 elements
        // S = qh.kh + ql.kh + qh.kl : concat-K 3-segment, TM=64 for occupancy
        gemm_nt<MODE_S, 64, 128, 3><<<dim3(16, 32, 2), 256, 0, stream>>>(
            qh + off, ql + off, qh + off, 512, 1048576LL,
            kh + off, kh + off, kl + off, 512, 1048576LL,
            S, 2048, 16777216LL, nullptr, 48,
            nullptr, nullptr, nullptr, nullptr, nullptr);
        softmax_rows<<<1024, 256, 0, stream>>>(S);
        gemm_nt<MODE_PV, 64, 64, 1><<<dim3(8, 32, 2), 256, 0, stream>>>(
            (const f16*)S, nullptr, nullptr, 4096, 8388608LL,
            vt + off, nullptr, nullptr, 2048, 1048576LL,
            outb + off, 512, 2097152LL, nullptr, 64,
            nullptr, nullptr, nullptr, nullptr, nullptr);
    }

    // hid = relu(out @ W1 + b1)
    gemm_nt<MODE_HID, 128, 128, 1><<<dim3(4, 256, 1), 256, 0, stream>>>(
        outb, nullptr, nullptr, 512, 0, W1t, nullptr, nullptr, 512, 0,
        hid, 512, 0, b1, 16, nullptr, nullptr, nullptr, nullptr, nullptr);
    // final = hid @ W2 + b2 -> f32 d_out
    gemm_nt<MODE_FIN, 128, 128, 1><<<dim3(4, 256, 1), 256, 0, stream>>>(
        hid, nullptr, nullptr, 512, 0, W2t, nullptr, nullptr, 512, 0,
        d_out, 512, 0, b2, 16, nullptr, nullptr, nullptr, nullptr, nullptr);
}

// Round 5
// 941.817 us; speedup vs baseline: 1.9032x; 1.9032x over previous
//
#include <hip/hip_runtime.h>
#include <cstdint>
#include <cstddef>

typedef _Float16 f16;
typedef __attribute__((ext_vector_type(8))) _Float16 f16x8;
typedef __attribute__((ext_vector_type(4))) _Float16 f16x4;
typedef __attribute__((ext_vector_type(4))) float f32x4;

#define AS1 const __attribute__((address_space(1))) void*
#define AS3 __attribute__((address_space(3))) void*

__device__ __forceinline__ void gld_lds16(const void* g, void* l) {
    __builtin_amdgcn_global_load_lds((AS1)g, (AS3)l, 16, 0, 0);
}

// ---------------- weight prep ----------------
__global__ __launch_bounds__(256) void prep_weights(
    const float* __restrict__ Wv, const float* __restrict__ Wk, const float* __restrict__ Wq,
    const float* __restrict__ W1, const float* __restrict__ W2,
    const float* __restrict__ bq, const float* __restrict__ bk, const float* __restrict__ bv,
    f16* __restrict__ Wqkv_h, f16* __restrict__ Wqkv_l,
    f16* __restrict__ W1t, f16* __restrict__ W2t, float* __restrict__ bias_qkv) {
    int i = blockIdx.x * 256 + threadIdx.x;
    if (i < 1536 * 512) {
        int j = i >> 9, m = i & 511;   // j = output col (q|k|v), m = k index
        float w = (j < 512) ? Wq[m * 512 + j]
               : (j < 1024) ? Wk[m * 512 + (j - 512)]
                            : Wv[m * 512 + (j - 1024)];
        f16 hi = (f16)w;
        Wqkv_h[i] = hi;
        Wqkv_l[i] = (f16)(w - (float)hi);
    }
    if (i < 512 * 512) {
        int j = i >> 9, m = i & 511;
        W1t[i] = (f16)W1[m * 512 + j];
        W2t[i] = (f16)W2[m * 512 + j];
    }
    if (i < 1536) {
        bias_qkv[i] = (i < 512) ? bq[i] : (i < 1024) ? bk[i - 512] : bv[i - 1024];
    }
}

// ---------------- GEMM (NT: C[i,j] = sum_k A[i,k]*B[j,k]) ----------------
// 128 x TN tile, BK=32, 4 waves (2x2), 16x16x32 f16 MFMA, double-buffered
// global_load_lds staging. MODE_QKV stages A as raw f32 and splits hi/lo
// in registers (exact); split-B modes run 3 MFMAs (Karatsuba, drop lo*lo).
// T1: bijective XCD-chunked blockIdx swizzle (m204) for L2 panel reuse.
enum { MODE_QKV = 0, MODE_S = 1, MODE_PV = 2, MODE_HID = 3, MODE_FIN = 4 };

template <int MODE, int TN>
__global__ __launch_bounds__(256, 2) void gemm_nt(
    const void* __restrict__ Av, const f16* __restrict__ Alp, int lda, long long sA,
    const f16* __restrict__ Bp, const f16* __restrict__ Blp, int ldb, long long sB,
    void* __restrict__ C, int ldc, long long sC,
    const float* __restrict__ bias, int K,
    f16* __restrict__ Qh, f16* __restrict__ Ql,
    f16* __restrict__ Kh, f16* __restrict__ Kl, f16* __restrict__ Vt)
{
    constexpr bool AF32 = (MODE == MODE_QKV);               // A staged as f32
    constexpr bool SPA  = (MODE == MODE_S);                 // A has hi/lo tiles
    constexpr bool SPB  = (MODE == MODE_QKV || MODE == MODE_S);
    constexpr int ABYTES = AF32 ? 128 * 32 * 4 : 128 * 32 * 2;
    constexpr int BBYTES = TN * 32 * 2;
    constexpr int NA = SPA ? 2 : 1;
    constexpr int NB = SPB ? 2 : 1;
    constexpr int NW = TN / 32;                             // n-frags per wave
    __shared__ alignas(16) char lds[2][NA * ABYTES + NB * BBYTES];

    const int lane = threadIdx.x & 63;
    const int wave = threadIdx.x >> 6;

    // ---- T1: XCD-chunked bijective swizzle (m204). Consecutive remapped ids
    // (x-fastest) land on ONE XCD -> row/col panel sharers hit the same L2.
    int bx = blockIdx.x, by = blockIdx.y, bz = blockIdx.z;
    {
        const int nx = gridDim.x, ny = gridDim.y;
        const int nwg = nx * ny * gridDim.z;
        const int lid = bx + nx * (by + ny * bz);
        const int q = nwg >> 3, r = nwg & 7;
        const int xcd = lid & 7, pos = lid >> 3;
        const int nid = (xcd < r ? xcd * (q + 1) : r * (q + 1) + (xcd - r) * q) + pos;
        bx = nid % nx; const int t = nid / nx; by = t % ny; bz = t / ny;
    }
    const int z = bz;

    const float* A32 = (const float*)Av;                    // AF32 (z==0 there)
    const f16* A = (const f16*)Av + (long long)z * sA;
    const f16* Al = nullptr;
    if constexpr (SPA) Al = Alp + (long long)z * sA;
    const f16* B = Bp + (long long)z * sB;
    const f16* Bl = nullptr;
    if constexpr (SPB) Bl = Blp + (long long)z * sB;
    char* Cb = (char*)C + (long long)z * sC;

    const int rowBase = by * 128;
    const int colBase = bx * TN;

    auto stage = [&](int buf, int kt) {
        char* base = lds[buf];
        const int k0 = kt << 5;
        if constexpr (AF32) {
            const int segr = lane >> 3;           // 8 rows per 1KB issue
            const int segk = (lane & 7) * 4;      // f32 elements
            #pragma unroll
            for (int c = 0; c < 4; ++c) {
                const int seg = wave * 4 + c;     // 0..15
                const int r = seg * 8 + segr;
                gld_lds16(A32 + (size_t)(rowBase + r) * lda + k0 + segk,
                          base + seg * 1024);
            }
        } else {
            const int segr = lane >> 2;           // 16 rows per 1KB issue
            const int segk = (lane & 3) * 8;      // f16 elements
            #pragma unroll
            for (int c = 0; c < 2; ++c) {
                const int seg = wave * 2 + c;     // 0..7
                const int r = seg * 16 + segr;
                const size_t off = (size_t)(rowBase + r) * lda + k0 + segk;
                gld_lds16(A + off, base + seg * 1024);
                if constexpr (SPA) gld_lds16(Al + off, base + ABYTES + seg * 1024);
            }
        }
        {
            char* bb = lds[buf] + NA * ABYTES;
            const int segr = lane >> 2;
            const int segk = (lane & 3) * 8;
            constexpr int CB = TN / 64;
            #pragma unroll
            for (int c = 0; c < CB; ++c) {
                const int seg = wave * CB + c;    // 0..TN/16-1
                const int r = seg * 16 + segr;
                const size_t off = (size_t)(colBase + r) * ldb + k0 + segk;
                gld_lds16(B + off, bb + seg * 1024);
                if constexpr (SPB) gld_lds16(Bl + off, bb + BBYTES + seg * 1024);
            }
        }
    };

    f32x4 acc[4][NW] = {};
    const int nK = K >> 5;
    stage(0, 0);

    const int wr = wave >> 1, wc = wave & 1;
    const int cl = lane & 15;
    const int kq = lane >> 4;
    const int kofs = kq * 8;

    for (int kt = 0; kt < nK; ++kt) {
        const int buf = kt & 1;
        __syncthreads();                          // drains vmcnt: buffer ready
        if (kt + 1 < nK) stage(buf ^ 1, kt + 1);

        f16x8 ah[4], alo[4], bh[NW], blo[NW];
        const char* bufp = lds[buf];
        if constexpr (AF32) {
            #pragma unroll
            for (int m = 0; m < 4; ++m) {
                const float* ap = (const float*)bufp + (wr * 64 + m * 16 + cl) * 32 + kofs;
                const f32x4 u = *(const f32x4*)ap;
                const f32x4 w = *(const f32x4*)(ap + 4);
                #pragma unroll
                for (int j = 0; j < 4; ++j) {
                    f16 h0 = (f16)u[j]; ah[m][j] = h0; alo[m][j] = (f16)(u[j] - (float)h0);
                    f16 h1 = (f16)w[j]; ah[m][4 + j] = h1; alo[m][4 + j] = (f16)(w[j] - (float)h1);
                }
            }
        } else {
            #pragma unroll
            for (int m = 0; m < 4; ++m) {
                const int eo = ((wr * 64 + m * 16 + cl) * 32 + kofs) * 2;
                ah[m] = *(const f16x8*)(bufp + eo);
                if constexpr (SPA) alo[m] = *(const f16x8*)(bufp + ABYTES + eo);
            }
        }
        {
            const char* bb = bufp + NA * ABYTES;
            #pragma unroll
            for (int n = 0; n < NW; ++n) {
                const int eo = ((wc * (TN / 2) + n * 16 + cl) * 32 + kofs) * 2;
                bh[n] = *(const f16x8*)(bb + eo);
                if constexpr (SPB) blo[n] = *(const f16x8*)(bb + BBYTES + eo);
            }
        }
        #pragma unroll
        for (int m = 0; m < 4; ++m)
            #pragma unroll
            for (int n = 0; n < NW; ++n) {
                acc[m][n] = __builtin_amdgcn_mfma_f32_16x16x32_f16(ah[m], bh[n], acc[m][n], 0, 0, 0);
                if constexpr (SPB)
                    acc[m][n] = __builtin_amdgcn_mfma_f32_16x16x32_f16(ah[m], blo[n], acc[m][n], 0, 0, 0);
                if constexpr (AF32 || SPA)
                    acc[m][n] = __builtin_amdgcn_mfma_f32_16x16x32_f16(alo[m], bh[n], acc[m][n], 0, 0, 0);
            }
    }

    // ---- epilogue: C/D layout col = lane&15, row = (lane>>4)*4 + j ----
    #pragma unroll
    for (int m = 0; m < 4; ++m) {
        #pragma unroll
        for (int n = 0; n < NW; ++n) {
            const f32x4 a = acc[m][n];
            const int col = colBase + wc * (TN / 2) + n * 16 + cl;
            float bval = 0.f;
            if constexpr (MODE == MODE_QKV || MODE == MODE_HID || MODE == MODE_FIN)
                bval = bias[col];
            #pragma unroll
            for (int j = 0; j < 4; ++j) {
                const int row = rowBase + wr * 64 + m * 16 + kq * 4 + j;
                const float v = a[j] + bval;
                if constexpr (MODE == MODE_S) {
                    ((float*)Cb)[(size_t)row * ldc + col] = v;
                } else if constexpr (MODE == MODE_PV) {
                    ((f16*)Cb)[(size_t)row * ldc + col] = (f16)v;
                } else if constexpr (MODE == MODE_HID) {
                    ((f16*)Cb)[(size_t)row * ldc + col] = (f16)fmaxf(v, 0.f);
                } else if constexpr (MODE == MODE_FIN) {
                    ((float*)Cb)[(size_t)row * ldc + col] = v;
                } else {  // MODE_QKV: cols [0,512)=q, [512,1024)=k, [1024,1536)=v^T
                    if (col < 1024) {
                        const f16 hi = (f16)v;
                        const f16 lo = (f16)(v - (float)hi);
                        const size_t idx = (size_t)row * 512 + (col & 511);
                        if (col < 512) { Qh[idx] = hi; Ql[idx] = lo; }
                        else           { Kh[idx] = hi; Kl[idx] = lo; }
                    } else {
                        Vt[((size_t)(row >> 11) * 512 + (col - 1024)) * 2048 + (row & 2047)] = (f16)v;
                    }
                }
            }
        }
    }
}

// ---------------- softmax over rows of S (2048 cols), P fp16 in place ----------------
__global__ __launch_bounds__(256) void softmax_rows(float* __restrict__ S) {
    const int wave = threadIdx.x >> 6, lane = threadIdx.x & 63;
    float* rp = S + ((size_t)blockIdx.x * 4 + wave) * 2048;
    f32x4 v[8];
    float mx = -3.0e38f;
    #pragma unroll
    for (int s = 0; s < 8; ++s) {
        v[s] = ((const f32x4*)rp)[s * 64 + lane];
        mx = fmaxf(mx, fmaxf(fmaxf(v[s][0], v[s][1]), fmaxf(v[s][2], v[s][3])));
    }
    #pragma unroll
    for (int off = 32; off; off >>= 1) mx = fmaxf(mx, __shfl_xor(mx, off));
    float sum = 0.f;
    #pragma unroll
    for (int s = 0; s < 8; ++s)
        #pragma unroll
        for (int j = 0; j < 4; ++j) { const float e = __expf(v[s][j] - mx); v[s][j] = e; sum += e; }
    #pragma unroll
    for (int off = 32; off; off >>= 1) sum += __shfl_xor(sum, off);
    const float inv = 1.0f / sum;
    f16* op = (f16*)rp;   // overwrite first half of the row with fp16 P
    #pragma unroll
    for (int s = 0; s < 8; ++s) {
        f16x4 o;
        #pragma unroll
        for (int j = 0; j < 4; ++j) o[j] = (f16)(v[s][j] * inv);
        ((f16x4*)op)[s * 64 + lane] = o;
    }
}

extern "C" void kernel_launch(void* const* d_in, const int* in_sizes, int n_in,
                              void* d_out, int out_size, void* d_ws, size_t ws_size,
                              hipStream_t stream) {
    const float* h  = (const float*)d_in[1];
    const float* Wv = (const float*)d_in[2];
    const float* bv = (const float*)d_in[3];
    const float* Wk = (const float*)d_in[4];
    const float* bk = (const float*)d_in[5];
    const float* Wq = (const float*)d_in[6];
    const float* bq = (const float*)d_in[7];
    const float* W1 = (const float*)d_in[8];
    const float* b1 = (const float*)d_in[9];
    const float* W2 = (const float*)d_in[10];
    const float* b2 = (const float*)d_in[11];

    // ---- workspace (~206 MB total; layout proven in round 3) ----
    char* p = (char*)d_ws;
    auto take = [&](size_t bytes) { char* r = p; p += (bytes + 255) & ~(size_t)255; return r; };

    const size_t QB = (size_t)32768 * 512 * 2;   // 32 MiB per qkv buffer
    f16* qh = (f16*)take(QB);
    f16* ql = (f16*)take(QB);
    f16* kh = (f16*)take(QB);
    f16* kl = (f16*)take(QB);
    f16* vt = (f16*)take(QB);                    // [b][h][n]
    float* S = (float*)take((size_t)2 * 2048 * 2048 * 4);   // 2-batch score chunk
    f16* Wqkvh = (f16*)take(1536 * 512 * 2);
    f16* Wqkvl = (f16*)take(1536 * 512 * 2);
    f16* W1t   = (f16*)take(512 * 512 * 2);
    f16* W2t   = (f16*)take(512 * 512 * 2);
    float* biasqkv = (float*)take(1536 * 4);
    // aliases (lifetime-disjoint per batch-slice, stream-ordered):
    f16* outb = kl;   // PV[b] writes after S-GEMM[b]'s last read of kl[b]
    f16* hid  = qh;   // MLP1 writes after last S-GEMM read of qh

    prep_weights<<<3072, 256, 0, stream>>>(Wv, Wk, Wq, W1, W2, bq, bk, bv,
                                           Wqkvh, Wqkvl, W1t, W2t, biasqkv);
    // q,k,v = h @ Wqkv + b : A = raw f32 h, exact hi/lo split in-register
    gemm_nt<MODE_QKV, 128><<<dim3(12, 256, 1), 256, 0, stream>>>(
        h, nullptr, 512, 0, Wqkvh, Wqkvl, 512, 0,
        nullptr, 0, 0, biasqkv, 512, qh, ql, kh, kl, vt);

    // attention, 2 batches per chunk (S region reused 8x)
    for (int c = 0; c < 8; ++c) {
        const long long off = (long long)c * 2 * 2048 * 512;  // f16 elements
        gemm_nt<MODE_S, 128><<<dim3(16, 16, 2), 256, 0, stream>>>(
            qh + off, ql + off, 512, 1048576LL,
            kh + off, kl + off, 512, 1048576LL,
            S, 2048, 16777216LL, nullptr, 512,
            nullptr, nullptr, nullptr, nullptr, nullptr);
        softmax_rows<<<1024, 256, 0, stream>>>(S);
        gemm_nt<MODE_PV, 64><<<dim3(8, 16, 2), 256, 0, stream>>>(
            (const f16*)S, nullptr, 4096, 8388608LL,
            vt + off, nullptr, 2048, 1048576LL,
            outb + off, 512, 2097152LL, nullptr, 2048,
            nullptr, nullptr, nullptr, nullptr, nullptr);
    }

    // hid = relu(out @ W1 + b1)
    gemm_nt<MODE_HID, 128><<<dim3(4, 256, 1), 256, 0, stream>>>(
        outb, nullptr, 512, 0, W1t, nullptr, 512, 0,
        hid, 512, 0, b1, 512, nullptr, nullptr, nullptr, nullptr, nullptr);
    // final = hid @ W2 + b2 -> f32 d_out
    gemm_nt<MODE_FIN, 128><<<dim3(4, 256, 1), 256, 0, stream>>>(
        hid, nullptr, 512, 0, W2t, nullptr, 512, 0,
        d_out, 512, 0, b2, 512, nullptr, nullptr, nullptr, nullptr, nullptr);
}

// Round 6
// 879.340 us; speedup vs baseline: 2.0385x; 1.0710x over previous
//
#include <hip/hip_runtime.h>
#include <cstdint>
#include <cstddef>

typedef _Float16 f16;
typedef __attribute__((ext_vector_type(8))) _Float16 f16x8;
typedef __attribute__((ext_vector_type(4))) _Float16 f16x4;
typedef __attribute__((ext_vector_type(4))) float f32x4;

#define AS1 const __attribute__((address_space(1))) void*
#define AS3 __attribute__((address_space(3))) void*

__device__ __forceinline__ void gld_lds16(const void* g, void* l) {
    __builtin_amdgcn_global_load_lds((AS1)g, (AS3)l, 16, 0, 0);
}

// ---------------- prep: cast h to fp16 ----------------
__global__ __launch_bounds__(256) void cast_h(const float* __restrict__ in,
                                              f16* __restrict__ hh, int n4) {
    int i = blockIdx.x * 256 + threadIdx.x;
    if (i >= n4) return;
    f32x4 x = ((const f32x4*)in)[i];
    f16x4 a;
    #pragma unroll
    for (int j = 0; j < 4; ++j) a[j] = (f16)x[j];
    ((f16x4*)hh)[i] = a;
}

// ---------------- weight prep ----------------
__global__ __launch_bounds__(256) void prep_weights(
    const float* __restrict__ Wv, const float* __restrict__ Wk, const float* __restrict__ Wq,
    const float* __restrict__ W1, const float* __restrict__ W2,
    const float* __restrict__ bq, const float* __restrict__ bk, const float* __restrict__ bv,
    f16* __restrict__ Wqkv_h, f16* __restrict__ Wqkv_l,
    f16* __restrict__ W1t, f16* __restrict__ W2t, float* __restrict__ bias_qkv) {
    int i = blockIdx.x * 256 + threadIdx.x;
    if (i < 1536 * 512) {
        int j = i >> 9, m = i & 511;   // j = output col (q|k|v), m = k index
        float w = (j < 512) ? Wq[m * 512 + j]
               : (j < 1024) ? Wk[m * 512 + (j - 512)]
                            : Wv[m * 512 + (j - 1024)];
        f16 hi = (f16)w;
        Wqkv_h[i] = hi;
        Wqkv_l[i] = (f16)(w - (float)hi);
    }
    if (i < 512 * 512) {
        int j = i >> 9, m = i & 511;
        W1t[i] = (f16)W1[m * 512 + j];
        W2t[i] = (f16)W2[m * 512 + j];
    }
    if (i < 1536) {
        bias_qkv[i] = (i < 512) ? bq[i] : (i < 1024) ? bk[i - 512] : bv[i - 1024];
    }
}

// ---------------- GEMM (NT: C[i,j] = sum_k A[i,k]*B[j,k]) ----------------
// 128 x TN tile, BK=32, 4 waves (2x2), 16x16x32 f16 MFMA, double-buffered
// global_load_lds staging.
//   MODE_QKV: A=fp16 h, B split hi/lo -> 2 MFMAs/acc (h-residual dropped;
//             measured absmax 0.03125 vs 0.075 threshold, round 4).
//   MODE_S:   A and B split -> 3 MFMAs/acc (Karatsuba, drop lo*lo) for
//             f32-accurate logits.
// T1: bijective XCD-chunked blockIdx swizzle (m204) for L2 panel reuse.
enum { MODE_QKV = 0, MODE_S = 1, MODE_PV = 2, MODE_HID = 3, MODE_FIN = 4 };

template <int MODE, int TN>
__global__ __launch_bounds__(256, 2) void gemm_nt(
    const f16* __restrict__ Ap, const f16* __restrict__ Alp, int lda, long long sA,
    const f16* __restrict__ Bp, const f16* __restrict__ Blp, int ldb, long long sB,
    void* __restrict__ C, int ldc, long long sC,
    const float* __restrict__ bias, int K,
    f16* __restrict__ Qh, f16* __restrict__ Ql,
    f16* __restrict__ Kh, f16* __restrict__ Kl, f16* __restrict__ Vt)
{
    constexpr bool SPA  = (MODE == MODE_S);                 // A has hi/lo tiles
    constexpr bool SPB  = (MODE == MODE_QKV || MODE == MODE_S);
    constexpr int ABYTES = 128 * 32 * 2;
    constexpr int BBYTES = TN * 32 * 2;
    constexpr int NA = SPA ? 2 : 1;
    constexpr int NB = SPB ? 2 : 1;
    constexpr int NW = TN / 32;                             // n-frags per wave
    __shared__ alignas(16) char lds[2][NA * ABYTES + NB * BBYTES];

    const int lane = threadIdx.x & 63;
    const int wave = threadIdx.x >> 6;

    // ---- T1: XCD-chunked bijective swizzle (m204). Consecutive remapped ids
    // (x-fastest) land on ONE XCD -> row/col panel sharers hit the same L2.
    int bx = blockIdx.x, by = blockIdx.y, bz = blockIdx.z;
    {
        const int nx = gridDim.x, ny = gridDim.y;
        const int nwg = nx * ny * gridDim.z;
        const int lid = bx + nx * (by + ny * bz);
        const int q = nwg >> 3, r = nwg & 7;
        const int xcd = lid & 7, pos = lid >> 3;
        const int nid = (xcd < r ? xcd * (q + 1) : r * (q + 1) + (xcd - r) * q) + pos;
        bx = nid % nx; const int t = nid / nx; by = t % ny; bz = t / ny;
    }
    const int z = bz;

    const f16* A = Ap + (long long)z * sA;
    const f16* Al = nullptr;
    if constexpr (SPA) Al = Alp + (long long)z * sA;
    const f16* B = Bp + (long long)z * sB;
    const f16* Bl = nullptr;
    if constexpr (SPB) Bl = Blp + (long long)z * sB;
    char* Cb = (char*)C + (long long)z * sC;

    const int rowBase = by * 128;
    const int colBase = bx * TN;

    const int segr = lane >> 2;               // 16 rows per 1KB issue
    const int segk = (lane & 3) * 8;          // f16 elements

    auto stage = [&](int buf, int kt) {
        char* base = lds[buf];
        const int k0 = kt << 5;
        #pragma unroll
        for (int c = 0; c < 2; ++c) {
            const int seg = wave * 2 + c;     // 0..7
            const int r = seg * 16 + segr;
            const size_t off = (size_t)(rowBase + r) * lda + k0 + segk;
            gld_lds16(A + off, base + seg * 1024);
            if constexpr (SPA) gld_lds16(Al + off, base + ABYTES + seg * 1024);
        }
        {
            char* bb = base + NA * ABYTES;
            constexpr int CB = TN / 64;
            #pragma unroll
            for (int c = 0; c < CB; ++c) {
                const int seg = wave * CB + c;    // 0..TN/16-1
                const int r = seg * 16 + segr;
                const size_t off = (size_t)(colBase + r) * ldb + k0 + segk;
                gld_lds16(B + off, bb + seg * 1024);
                if constexpr (SPB) gld_lds16(Bl + off, bb + BBYTES + seg * 1024);
            }
        }
    };

    f32x4 acc[4][NW] = {};
    const int nK = K >> 5;
    stage(0, 0);

    const int wr = wave >> 1, wc = wave & 1;
    const int cl = lane & 15;
    const int kq = lane >> 4;
    const int kofs = kq * 8;

    for (int kt = 0; kt < nK; ++kt) {
        const int buf = kt & 1;
        __syncthreads();                          // drains vmcnt: buffer ready
        if (kt + 1 < nK) stage(buf ^ 1, kt + 1);

        f16x8 ah[4], alo[4], bh[NW], blo[NW];
        const char* bufp = lds[buf];
        #pragma unroll
        for (int m = 0; m < 4; ++m) {
            const int eo = ((wr * 64 + m * 16 + cl) * 32 + kofs) * 2;
            ah[m] = *(const f16x8*)(bufp + eo);
            if constexpr (SPA) alo[m] = *(const f16x8*)(bufp + ABYTES + eo);
        }
        {
            const char* bb = bufp + NA * ABYTES;
            #pragma unroll
            for (int n = 0; n < NW; ++n) {
                const int eo = ((wc * (TN / 2) + n * 16 + cl) * 32 + kofs) * 2;
                bh[n] = *(const f16x8*)(bb + eo);
                if constexpr (SPB) blo[n] = *(const f16x8*)(bb + BBYTES + eo);
            }
        }
        #pragma unroll
        for (int m = 0; m < 4; ++m)
            #pragma unroll
            for (int n = 0; n < NW; ++n) {
                acc[m][n] = __builtin_amdgcn_mfma_f32_16x16x32_f16(ah[m], bh[n], acc[m][n], 0, 0, 0);
                if constexpr (SPB)
                    acc[m][n] = __builtin_amdgcn_mfma_f32_16x16x32_f16(ah[m], blo[n], acc[m][n], 0, 0, 0);
                if constexpr (SPA)
                    acc[m][n] = __builtin_amdgcn_mfma_f32_16x16x32_f16(alo[m], bh[n], acc[m][n], 0, 0, 0);
            }
    }

    // ---- epilogue: C/D layout col = lane&15, row = (lane>>4)*4 + j ----
    #pragma unroll
    for (int m = 0; m < 4; ++m) {
        #pragma unroll
        for (int n = 0; n < NW; ++n) {
            const f32x4 a = acc[m][n];
            const int col = colBase + wc * (TN / 2) + n * 16 + cl;
            float bval = 0.f;
            if constexpr (MODE == MODE_QKV || MODE == MODE_HID || MODE == MODE_FIN)
                bval = bias[col];
            #pragma unroll
            for (int j = 0; j < 4; ++j) {
                const int row = rowBase + wr * 64 + m * 16 + kq * 4 + j;
                const float v = a[j] + bval;
                if constexpr (MODE == MODE_S) {
                    ((float*)Cb)[(size_t)row * ldc + col] = v;
                } else if constexpr (MODE == MODE_PV) {
                    ((f16*)Cb)[(size_t)row * ldc + col] = (f16)v;
                } else if constexpr (MODE == MODE_HID) {
                    ((f16*)Cb)[(size_t)row * ldc + col] = (f16)fmaxf(v, 0.f);
                } else if constexpr (MODE == MODE_FIN) {
                    ((float*)Cb)[(size_t)row * ldc + col] = v;
                } else {  // MODE_QKV: cols [0,512)=q, [512,1024)=k, [1024,1536)=v^T
                    if (col < 1024) {
                        const f16 hi = (f16)v;
                        const f16 lo = (f16)(v - (float)hi);
                        const size_t idx = (size_t)row * 512 + (col & 511);
                        if (col < 512) { Qh[idx] = hi; Ql[idx] = lo; }
                        else           { Kh[idx] = hi; Kl[idx] = lo; }
                    } else {
                        Vt[((size_t)(row >> 11) * 512 + (col - 1024)) * 2048 + (row & 2047)] = (f16)v;
                    }
                }
            }
        }
    }
}

// ---------------- softmax over rows of S (2048 cols), P fp16 in place ----------------
__global__ __launch_bounds__(256) void softmax_rows(float* __restrict__ S) {
    const int wave = threadIdx.x >> 6, lane = threadIdx.x & 63;
    float* rp = S + ((size_t)blockIdx.x * 4 + wave) * 2048;
    f32x4 v[8];
    float mx = -3.0e38f;
    #pragma unroll
    for (int s = 0; s < 8; ++s) {
        v[s] = ((const f32x4*)rp)[s * 64 + lane];
        mx = fmaxf(mx, fmaxf(fmaxf(v[s][0], v[s][1]), fmaxf(v[s][2], v[s][3])));
    }
    #pragma unroll
    for (int off = 32; off; off >>= 1) mx = fmaxf(mx, __shfl_xor(mx, off));
    float sum = 0.f;
    #pragma unroll
    for (int s = 0; s < 8; ++s)
        #pragma unroll
        for (int j = 0; j < 4; ++j) { const float e = __expf(v[s][j] - mx); v[s][j] = e; sum += e; }
    #pragma unroll
    for (int off = 32; off; off >>= 1) sum += __shfl_xor(sum, off);
    const float inv = 1.0f / sum;
    f16* op = (f16*)rp;   // overwrite first half of the row with fp16 P
    #pragma unroll
    for (int s = 0; s < 8; ++s) {
        f16x4 o;
        #pragma unroll
        for (int j = 0; j < 4; ++j) o[j] = (f16)(v[s][j] * inv);
        ((f16x4*)op)[s * 64 + lane] = o;
    }
}

extern "C" void kernel_launch(void* const* d_in, const int* in_sizes, int n_in,
                              void* d_out, int out_size, void* d_ws, size_t ws_size,
                              hipStream_t stream) {
    const float* h  = (const float*)d_in[1];
    const float* Wv = (const float*)d_in[2];
    const float* bv = (const float*)d_in[3];
    const float* Wk = (const float*)d_in[4];
    const float* bk = (const float*)d_in[5];
    const float* Wq = (const float*)d_in[6];
    const float* bq = (const float*)d_in[7];
    const float* W1 = (const float*)d_in[8];
    const float* b1 = (const float*)d_in[9];
    const float* W2 = (const float*)d_in[10];
    const float* b2 = (const float*)d_in[11];

    // ---- workspace (~196 MB total; layout proven in rounds 3/5) ----
    char* p = (char*)d_ws;
    auto take = [&](size_t bytes) { char* r = p; p += (bytes + 255) & ~(size_t)255; return r; };

    const size_t QB = (size_t)32768 * 512 * 2;   // 32 MiB per qkv buffer
    f16* qh = (f16*)take(QB);
    f16* ql = (f16*)take(QB);
    f16* kh = (f16*)take(QB);
    f16* kl = (f16*)take(QB);
    f16* vt = (f16*)take(QB);                    // [b][h][n]
    float* S = (float*)take((size_t)2 * 2048 * 2048 * 4);   // 2-batch score chunk
    f16* Wqkvh = (f16*)take(1536 * 512 * 2);
    f16* Wqkvl = (f16*)take(1536 * 512 * 2);
    f16* W1t   = (f16*)take(512 * 512 * 2);
    f16* W2t   = (f16*)take(512 * 512 * 2);
    float* biasqkv = (float*)take(1536 * 4);
    // aliases (lifetime-disjoint per batch-slice, stream-ordered):
    f16* hh   = (f16*)S;  // fp16 h lives in S region until QKV completes (32 MiB exact)
    f16* outb = kl;       // PV[b] writes after S-GEMM[b]'s last read of kl[b]
    f16* hid  = qh;       // MLP1 writes after last S-GEMM read of qh

    cast_h<<<16384, 256, 0, stream>>>(h, hh, 4194304);
    prep_weights<<<3072, 256, 0, stream>>>(Wv, Wk, Wq, W1, W2, bq, bk, bv,
                                           Wqkvh, Wqkvl, W1t, W2t, biasqkv);
    // q,k,v = hh @ (Wh + Wl) + b : fp16 A, split B, 2 MFMAs/acc, LDS 48 KB
    gemm_nt<MODE_QKV, 128><<<dim3(12, 256, 1), 256, 0, stream>>>(
        hh, nullptr, 512, 0, Wqkvh, Wqkvl, 512, 0,
        nullptr, 0, 0, biasqkv, 512, qh, ql, kh, kl, vt);

    // attention, 2 batches per chunk (S region reused 8x)
    for (int c = 0; c < 8; ++c) {
        const long long off = (long long)c * 2 * 2048 * 512;  // f16 elements
        gemm_nt<MODE_S, 128><<<dim3(16, 16, 2), 256, 0, stream>>>(
            qh + off, ql + off, 512, 1048576LL,
            kh + off, kl + off, 512, 1048576LL,
            S, 2048, 16777216LL, nullptr, 512,
            nullptr, nullptr, nullptr, nullptr, nullptr);
        softmax_rows<<<1024, 256, 0, stream>>>(S);
        gemm_nt<MODE_PV, 64><<<dim3(8, 16, 2), 256, 0, stream>>>(
            (const f16*)S, nullptr, 4096, 8388608LL,
            vt + off, nullptr, 2048, 1048576LL,
            outb + off, 512, 2097152LL, nullptr, 2048,
            nullptr, nullptr, nullptr, nullptr, nullptr);
    }

    // hid = relu(out @ W1 + b1)
    gemm_nt<MODE_HID, 128><<<dim3(4, 256, 1), 256, 0, stream>>>(
        outb, nullptr, 512, 0, W1t, nullptr, 512, 0,
        hid, 512, 0, b1, 512, nullptr, nullptr, nullptr, nullptr, nullptr);
    // final = hid @ W2 + b2 -> f32 d_out
    gemm_nt<MODE_FIN, 128><<<dim3(4, 256, 1), 256, 0, stream>>>(
        hid, nullptr, 512, 0, W2t, nullptr, 512, 0,
        d_out, 512, 0, b2, 512, nullptr, nullptr, nullptr, nullptr, nullptr);
}

// Round 7
// 814.039 us; speedup vs baseline: 2.2020x; 1.0802x over previous
//
#include <hip/hip_runtime.h>
#include <cstdint>
#include <cstddef>

typedef _Float16 f16;
typedef __attribute__((ext_vector_type(8))) _Float16 f16x8;
typedef __attribute__((ext_vector_type(4))) _Float16 f16x4;
typedef __attribute__((ext_vector_type(4))) float f32x4;

#define AS1 const __attribute__((address_space(1))) void*
#define AS3 __attribute__((address_space(3))) void*

__device__ __forceinline__ void gld_lds16(const void* g, void* l) {
    __builtin_amdgcn_global_load_lds((AS1)g, (AS3)l, 16, 0, 0);
}

// ---------------- prep: cast h to fp16 ----------------
__global__ __launch_bounds__(256) void cast_h(const float* __restrict__ in,
                                              f16* __restrict__ hh, int n4) {
    int i = blockIdx.x * 256 + threadIdx.x;
    if (i >= n4) return;
    f32x4 x = ((const f32x4*)in)[i];
    f16x4 a;
    #pragma unroll
    for (int j = 0; j < 4; ++j) a[j] = (f16)x[j];
    ((f16x4*)hh)[i] = a;
}

// ---------------- weight prep ----------------
__global__ __launch_bounds__(256) void prep_weights(
    const float* __restrict__ Wv, const float* __restrict__ Wk, const float* __restrict__ Wq,
    const float* __restrict__ W1, const float* __restrict__ W2,
    const float* __restrict__ bq, const float* __restrict__ bk, const float* __restrict__ bv,
    f16* __restrict__ Wqkv_h, f16* __restrict__ Wqkv_l,
    f16* __restrict__ W1t, f16* __restrict__ W2t, float* __restrict__ bias_qkv) {
    int i = blockIdx.x * 256 + threadIdx.x;
    if (i < 1536 * 512) {
        int j = i >> 9, m = i & 511;   // j = output col (q|k|v), m = k index
        float w = (j < 512) ? Wq[m * 512 + j]
               : (j < 1024) ? Wk[m * 512 + (j - 512)]
                            : Wv[m * 512 + (j - 1024)];
        f16 hi = (f16)w;
        Wqkv_h[i] = hi;
        Wqkv_l[i] = (f16)(w - (float)hi);
    }
    if (i < 512 * 512) {
        int j = i >> 9, m = i & 511;
        W1t[i] = (f16)W1[m * 512 + j];
        W2t[i] = (f16)W2[m * 512 + j];
    }
    if (i < 1536) {
        bias_qkv[i] = (i < 512) ? bq[i] : (i < 1024) ? bk[i - 512] : bv[i - 1024];
    }
}

// ---------------- GEMM (NT: C[i,j] = sum_k A[i,k]*B[j,k]) ----------------
// 128 x TN tile, BK=32, 4 waves (2x2), 16x16x32 f16 MFMA, double-buffered
// global_load_lds staging.
//   MODE_QKV: A=fp16 h, B=W split hi/lo -> 2 MFMAs/acc (h-residual dropped).
//   MODE_S:   A=q split hi/lo, B=kh    -> 2 MFMAs/acc (qh*kl term dropped;
//             predicted logit err ~7.6e-3 sigma -> absmax ~0.045 < 0.075).
// All split modes: LDS 48 KB -> 3 blocks/CU.
// T1: bijective XCD-chunked blockIdx swizzle (m204) for L2 panel reuse.
enum { MODE_QKV = 0, MODE_S = 1, MODE_PV = 2, MODE_HID = 3, MODE_FIN = 4 };

template <int MODE, int TN>
__global__ __launch_bounds__(256, 2) void gemm_nt(
    const f16* __restrict__ Ap, const f16* __restrict__ Alp, int lda, long long sA,
    const f16* __restrict__ Bp, const f16* __restrict__ Blp, int ldb, long long sB,
    void* __restrict__ C, int ldc, long long sC,
    const float* __restrict__ bias, int K,
    f16* __restrict__ Qh, f16* __restrict__ Ql,
    f16* __restrict__ Kh, f16* __restrict__ Vt)
{
    constexpr bool SPA  = (MODE == MODE_S);      // A has hi/lo tiles
    constexpr bool SPB  = (MODE == MODE_QKV);    // B has hi/lo tiles
    constexpr int ABYTES = 128 * 32 * 2;
    constexpr int BBYTES = TN * 32 * 2;
    constexpr int NA = SPA ? 2 : 1;
    constexpr int NB = SPB ? 2 : 1;
    constexpr int NW = TN / 32;                  // n-frags per wave
    __shared__ alignas(16) char lds[2][NA * ABYTES + NB * BBYTES];

    const int lane = threadIdx.x & 63;
    const int wave = threadIdx.x >> 6;

    // ---- T1: XCD-chunked bijective swizzle (m204). Consecutive remapped ids
    // (x-fastest) land on ONE XCD -> row/col panel sharers hit the same L2.
    int bx = blockIdx.x, by = blockIdx.y, bz = blockIdx.z;
    {
        const int nx = gridDim.x, ny = gridDim.y;
        const int nwg = nx * ny * gridDim.z;
        const int lid = bx + nx * (by + ny * bz);
        const int q = nwg >> 3, r = nwg & 7;
        const int xcd = lid & 7, pos = lid >> 3;
        const int nid = (xcd < r ? xcd * (q + 1) : r * (q + 1) + (xcd - r) * q) + pos;
        bx = nid % nx; const int t = nid / nx; by = t % ny; bz = t / ny;
    }
    const int z = bz;

    const f16* A = Ap + (long long)z * sA;
    const f16* Al = nullptr;
    if constexpr (SPA) Al = Alp + (long long)z * sA;
    const f16* B = Bp + (long long)z * sB;
    const f16* Bl = nullptr;
    if constexpr (SPB) Bl = Blp;                 // weights: no z stride
    char* Cb = (char*)C + (long long)z * sC;

    const int rowBase = by * 128;
    const int colBase = bx * TN;

    const int segr = lane >> 2;               // 16 rows per 1KB issue
    const int segk = (lane & 3) * 8;          // f16 elements

    auto stage = [&](int buf, int kt) {
        char* base = lds[buf];
        const int k0 = kt << 5;
        #pragma unroll
        for (int c = 0; c < 2; ++c) {
            const int seg = wave * 2 + c;     // 0..7
            const int r = seg * 16 + segr;
            const size_t off = (size_t)(rowBase + r) * lda + k0 + segk;
            gld_lds16(A + off, base + seg * 1024);
            if constexpr (SPA) gld_lds16(Al + off, base + ABYTES + seg * 1024);
        }
        {
            char* bb = base + NA * ABYTES;
            constexpr int CB = TN / 64;
            #pragma unroll
            for (int c = 0; c < CB; ++c) {
                const int seg = wave * CB + c;    // 0..TN/16-1
                const int r = seg * 16 + segr;
                const size_t off = (size_t)(colBase + r) * ldb + k0 + segk;
                gld_lds16(B + off, bb + seg * 1024);
                if constexpr (SPB) gld_lds16(Bl + off, bb + BBYTES + seg * 1024);
            }
        }
    };

    f32x4 acc[4][NW] = {};
    const int nK = K >> 5;
    stage(0, 0);

    const int wr = wave >> 1, wc = wave & 1;
    const int cl = lane & 15;
    const int kq = lane >> 4;
    const int kofs = kq * 8;

    for (int kt = 0; kt < nK; ++kt) {
        const int buf = kt & 1;
        __syncthreads();                          // drains vmcnt: buffer ready
        if (kt + 1 < nK) stage(buf ^ 1, kt + 1);

        f16x8 ah[4], alo[4], bh[NW], blo[NW];
        const char* bufp = lds[buf];
        #pragma unroll
        for (int m = 0; m < 4; ++m) {
            const int eo = ((wr * 64 + m * 16 + cl) * 32 + kofs) * 2;
            ah[m] = *(const f16x8*)(bufp + eo);
            if constexpr (SPA) alo[m] = *(const f16x8*)(bufp + ABYTES + eo);
        }
        {
            const char* bb = bufp + NA * ABYTES;
            #pragma unroll
            for (int n = 0; n < NW; ++n) {
                const int eo = ((wc * (TN / 2) + n * 16 + cl) * 32 + kofs) * 2;
                bh[n] = *(const f16x8*)(bb + eo);
                if constexpr (SPB) blo[n] = *(const f16x8*)(bb + BBYTES + eo);
            }
        }
        #pragma unroll
        for (int m = 0; m < 4; ++m)
            #pragma unroll
            for (int n = 0; n < NW; ++n) {
                acc[m][n] = __builtin_amdgcn_mfma_f32_16x16x32_f16(ah[m], bh[n], acc[m][n], 0, 0, 0);
                if constexpr (SPB)
                    acc[m][n] = __builtin_amdgcn_mfma_f32_16x16x32_f16(ah[m], blo[n], acc[m][n], 0, 0, 0);
                if constexpr (SPA)
                    acc[m][n] = __builtin_amdgcn_mfma_f32_16x16x32_f16(alo[m], bh[n], acc[m][n], 0, 0, 0);
            }
    }

    // ---- epilogue: C/D layout col = lane&15, row = (lane>>4)*4 + j ----
    #pragma unroll
    for (int m = 0; m < 4; ++m) {
        #pragma unroll
        for (int n = 0; n < NW; ++n) {
            const f32x4 a = acc[m][n];
            const int col = colBase + wc * (TN / 2) + n * 16 + cl;
            float bval = 0.f;
            if constexpr (MODE == MODE_QKV || MODE == MODE_HID || MODE == MODE_FIN)
                bval = bias[col];
            #pragma unroll
            for (int j = 0; j < 4; ++j) {
                const int row = rowBase + wr * 64 + m * 16 + kq * 4 + j;
                const float v = a[j] + bval;
                if constexpr (MODE == MODE_S) {
                    ((float*)Cb)[(size_t)row * ldc + col] = v;
                } else if constexpr (MODE == MODE_PV) {
                    ((f16*)Cb)[(size_t)row * ldc + col] = (f16)v;
                } else if constexpr (MODE == MODE_HID) {
                    ((f16*)Cb)[(size_t)row * ldc + col] = (f16)fmaxf(v, 0.f);
                } else if constexpr (MODE == MODE_FIN) {
                    ((float*)Cb)[(size_t)row * ldc + col] = v;
                } else {  // MODE_QKV: cols [0,512)=q, [512,1024)=k, [1024,1536)=v^T
                    if (col < 1024) {
                        const size_t idx = (size_t)row * 512 + (col & 511);
                        if (col < 512) {
                            const f16 hi = (f16)v;
                            Qh[idx] = hi;
                            Ql[idx] = (f16)(v - (float)hi);
                        } else {
                            Kh[idx] = (f16)v;   // k residual not needed (2-term S)
                        }
                    } else {
                        Vt[((size_t)(row >> 11) * 512 + (col - 1024)) * 2048 + (row & 2047)] = (f16)v;
                    }
                }
            }
        }
    }
}

// ---------------- softmax over rows of S (2048 cols), P fp16 in place ----------------
__global__ __launch_bounds__(256) void softmax_rows(float* __restrict__ S) {
    const int wave = threadIdx.x >> 6, lane = threadIdx.x & 63;
    float* rp = S + ((size_t)blockIdx.x * 4 + wave) * 2048;
    f32x4 v[8];
    float mx = -3.0e38f;
    #pragma unroll
    for (int s = 0; s < 8; ++s) {
        v[s] = ((const f32x4*)rp)[s * 64 + lane];
        mx = fmaxf(mx, fmaxf(fmaxf(v[s][0], v[s][1]), fmaxf(v[s][2], v[s][3])));
    }
    #pragma unroll
    for (int off = 32; off; off >>= 1) mx = fmaxf(mx, __shfl_xor(mx, off));
    float sum = 0.f;
    #pragma unroll
    for (int s = 0; s < 8; ++s)
        #pragma unroll
        for (int j = 0; j < 4; ++j) { const float e = __expf(v[s][j] - mx); v[s][j] = e; sum += e; }
    #pragma unroll
    for (int off = 32; off; off >>= 1) sum += __shfl_xor(sum, off);
    const float inv = 1.0f / sum;
    f16* op = (f16*)rp;   // overwrite first half of the row with fp16 P
    #pragma unroll
    for (int s = 0; s < 8; ++s) {
        f16x4 o;
        #pragma unroll
        for (int j = 0; j < 4; ++j) o[j] = (f16)(v[s][j] * inv);
        ((f16x4*)op)[s * 64 + lane] = o;
    }
}

extern "C" void kernel_launch(void* const* d_in, const int* in_sizes, int n_in,
                              void* d_out, int out_size, void* d_ws, size_t ws_size,
                              hipStream_t stream) {
    const float* h  = (const float*)d_in[1];
    const float* Wv = (const float*)d_in[2];
    const float* bv = (const float*)d_in[3];
    const float* Wk = (const float*)d_in[4];
    const float* bk = (const float*)d_in[5];
    const float* Wq = (const float*)d_in[6];
    const float* bq = (const float*)d_in[7];
    const float* W1 = (const float*)d_in[8];
    const float* b1 = (const float*)d_in[9];
    const float* W2 = (const float*)d_in[10];
    const float* b2 = (const float*)d_in[11];

    // ---- workspace (~196 MB total; layout proven in rounds 3/5/6) ----
    char* p = (char*)d_ws;
    auto take = [&](size_t bytes) { char* r = p; p += (bytes + 255) & ~(size_t)255; return r; };

    const size_t QB = (size_t)32768 * 512 * 2;   // 32 MiB per qkv buffer
    f16* qh   = (f16*)take(QB);
    f16* ql   = (f16*)take(QB);
    f16* kh   = (f16*)take(QB);
    f16* outb = (f16*)take(QB);                  // attention output (own buffer now)
    f16* vt   = (f16*)take(QB);                  // [b][h][n]
    float* S = (float*)take((size_t)2 * 2048 * 2048 * 4);   // 2-batch score chunk
    f16* Wqkvh = (f16*)take(1536 * 512 * 2);
    f16* Wqkvl = (f16*)take(1536 * 512 * 2);
    f16* W1t   = (f16*)take(512 * 512 * 2);
    f16* W2t   = (f16*)take(512 * 512 * 2);
    float* biasqkv = (float*)take(1536 * 4);
    // aliases (lifetime-disjoint, stream-ordered):
    f16* hh  = (f16*)S;  // fp16 h lives in S region until QKV completes (32 MiB exact)
    f16* hid = qh;       // MLP1 writes after last S-GEMM read of qh

    cast_h<<<16384, 256, 0, stream>>>(h, hh, 4194304);
    prep_weights<<<3072, 256, 0, stream>>>(Wv, Wk, Wq, W1, W2, bq, bk, bv,
                                           Wqkvh, Wqkvl, W1t, W2t, biasqkv);
    // q,k,v = hh @ (Wh + Wl) + b : fp16 A, split B, 2 MFMAs/acc, LDS 48 KB
    gemm_nt<MODE_QKV, 128><<<dim3(12, 256, 1), 256, 0, stream>>>(
        hh, nullptr, 512, 0, Wqkvh, Wqkvl, 512, 0,
        nullptr, 0, 0, biasqkv, 512, qh, ql, kh, vt);

    // attention, 2 batches per chunk (S region reused 8x)
    for (int c = 0; c < 8; ++c) {
        const long long off = (long long)c * 2 * 2048 * 512;  // f16 elements
        // S = qh.kh + ql.kh : split A, 2 MFMAs/acc, LDS 48 KB
        gemm_nt<MODE_S, 128><<<dim3(16, 16, 2), 256, 0, stream>>>(
            qh + off, ql + off, 512, 1048576LL,
            kh + off, nullptr, 512, 1048576LL,
            S, 2048, 16777216LL, nullptr, 512,
            nullptr, nullptr, nullptr, nullptr);
        softmax_rows<<<1024, 256, 0, stream>>>(S);
        gemm_nt<MODE_PV, 64><<<dim3(8, 16, 2), 256, 0, stream>>>(
            (const f16*)S, nullptr, 4096, 8388608LL,
            vt + off, nullptr, 2048, 1048576LL,
            outb + off, 512, 2097152LL, nullptr, 2048,
            nullptr, nullptr, nullptr, nullptr);
    }

    // hid = relu(out @ W1 + b1)
    gemm_nt<MODE_HID, 128><<<dim3(4, 256, 1), 256, 0, stream>>>(
        outb, nullptr, 512, 0, W1t, nullptr, 512, 0,
        hid, 512, 0, b1, 512, nullptr, nullptr, nullptr, nullptr);
    // final = hid @ W2 + b2 -> f32 d_out
    gemm_nt<MODE_FIN, 128><<<dim3(4, 256, 1), 256, 0, stream>>>(
        hid, nullptr, 512, 0, W2t, nullptr, 512, 0,
        d_out, 512, 0, b2, 512, nullptr, nullptr, nullptr, nullptr);
}